// Round 7
// baseline (114.312 us; speedup 1.0000x reference)
//
#include <hip/hip_runtime.h>
#include <hip/hip_bf16.h>

// GraphSAGE 2-layer forward, restructured algebraically:
//   P = [feats @ Wx1 | feats @ Wn1]  (bf16, whole table, streaming MFMA GEMM)
//   h1[r] = relu([Px[ids1[r]] + bx ; mean10(Pn[ids2]) + bn])   (gather-add)
//   h0    = relu([Px[ids]     + bx ; mean25(Pn[ids1]) + bn])
//   g0    = [h0 @ Wx2 + b ; mean25(h1) @ Wn2 + b]; out = normalize(g0) @ Wfc + bfc
// mean(X) @ W == mean(X @ W) since mean is linear; bias/relu applied after.

typedef __bf16 bf16x8 __attribute__((ext_vector_type(8)));
typedef __bf16 bf16x4 __attribute__((ext_vector_type(4)));
typedef __bf16 bf16x2 __attribute__((ext_vector_type(2)));
typedef float  f32x4  __attribute__((ext_vector_type(4)));

constexpr int IN    = 256;
constexpr int HIDC  = 128;
constexpr int NNODE = 100000;
constexpr int ROWS1 = 512 * 25;   // 12800

// ---------------- Kernel P0: Wt = [Wx1|Wn1] columns as bf16 hi/lo -----------
// WtH/WtL[j][k], j in [0,256): j<128 -> Wx1 col j, else Wn1 col j-128.
__global__ __launch_bounds__(256) void k_wprep(
    const float* __restrict__ Wx, const float* __restrict__ Wn,
    __bf16* __restrict__ WtH, __bf16* __restrict__ WtL)
{
    const int j = blockIdx.x;
    const int k = threadIdx.x;
    const float v = (j < HIDC) ? Wx[(size_t)k * HIDC + j]
                               : Wn[(size_t)k * HIDC + (j - HIDC)];
    const __bf16 h = (__bf16)v;
    const __bf16 l = (__bf16)(v - (float)h);
    const size_t o = (size_t)j * IN + k;
    WtH[o] = h;
    WtL[o] = l;
}

// ---------------- Kernel P: P = feats @ [Wx1|Wn1]  (bf16 out) ---------------
// 64 rows/block, 256 thr = 4 waves; wave w -> cols w*64..+63 (4 tiles) x
// 4 row-tiles. A staged bf16-hi in LDS with 16B-slot XOR swizzle; W 2-pass
// (hi+lo) MFMA. Streaming: feats rows contiguous per block.
__global__ __launch_bounds__(256) void k_P(
    const float* __restrict__ feats,
    const __bf16* __restrict__ WtH, const __bf16* __restrict__ WtL,
    __bf16* __restrict__ P)
{
    __shared__ __bf16 As[64 * IN];
    const int tid = threadIdx.x;
    const int r0  = blockIdx.x * 64;

    #pragma unroll
    for (int i = 0; i < 16; ++i) {
        const int idx = tid + i * 256;          // float4 index within tile
        const int row = idx >> 6, sub = idx & 63;
        const int r   = min(r0 + row, NNODE - 1);
        const float4 v = ((const float4*)(feats + (size_t)r * IN))[sub];
        const bf16x4 hv = {(__bf16)v.x, (__bf16)v.y, (__bf16)v.z, (__bf16)v.w};
        const int e = (row << 8) + sub * 4;
        *(bf16x4*)&As[e ^ ((row & 7) << 3)] = hv;
    }
    __syncthreads();

    const int lane = tid & 63;
    const int wid  = tid >> 6;
    const int l15  = lane & 15;
    const int lk   = lane >> 4;

    const f32x4 z = {0.f, 0.f, 0.f, 0.f};
    f32x4 acc[4][4];
    #pragma unroll
    for (int rt = 0; rt < 4; ++rt)
        #pragma unroll
        for (int ct = 0; ct < 4; ++ct) acc[rt][ct] = z;

    for (int k0 = 0; k0 < IN; k0 += 32) {
        bf16x8 a[4];
        #pragma unroll
        for (int rt = 0; rt < 4; ++rt) {
            int ea = ((rt * 16 + l15) << 8) + k0 + lk * 8;
            ea ^= (l15 & 7) << 3;               // (rt*16+l15)&7 == l15&7
            a[rt] = *(const bf16x8*)&As[ea];
        }
        #pragma unroll
        for (int ct = 0; ct < 4; ++ct) {
            const size_t eb = (size_t)(wid * 64 + ct * 16 + l15) * IN + k0 + lk * 8;
            const bf16x8 bH = *(const bf16x8*)&WtH[eb];
            const bf16x8 bL = *(const bf16x8*)&WtL[eb];
            #pragma unroll
            for (int rt = 0; rt < 4; ++rt) {
                acc[rt][ct] = __builtin_amdgcn_mfma_f32_16x16x32_bf16(a[rt], bH, acc[rt][ct], 0, 0, 0);
                acc[rt][ct] = __builtin_amdgcn_mfma_f32_16x16x32_bf16(a[rt], bL, acc[rt][ct], 0, 0, 0);
            }
        }
    }

    // epilogue: C/D col=lane&15, row=(lane>>4)*4+reg
    #pragma unroll
    for (int rt = 0; rt < 4; ++rt) {
        #pragma unroll
        for (int ct = 0; ct < 4; ++ct) {
            const int j = wid * 64 + ct * 16 + l15;
            #pragma unroll
            for (int q = 0; q < 4; ++q) {
                const int r = r0 + rt * 16 + lk * 4 + q;
                if (r < NNODE) P[(size_t)r * IN + j] = (__bf16)acc[rt][ct][q];
            }
        }
    }
}

// ---------------- Kernel H: h1 assembly (gather-add, one wave/row) ----------
// h1[r] = relu([Px[ids1[r]] + bx ; mean10(Pn[ids2 slice]) + bn]), bf16.
// Per wave: 11 independent 256B gathers; lane handles col pair {2l, 2l+1}.
__global__ __launch_bounds__(512) void k_h1s(
    const int* __restrict__ ids1, const int* __restrict__ ids2,
    const __bf16* __restrict__ P,
    const float* __restrict__ bx, const float* __restrict__ bn,
    __bf16* __restrict__ h1)
{
    const int r    = blockIdx.x * 8 + (threadIdx.x >> 6);
    const int lane = threadIdx.x & 63;
    const int base = r * 10;

    const float2 bxv = ((const float2*)bx)[lane];
    const float2 bnv = ((const float2*)bn)[lane];

    const bf16x2 vx = *(const bf16x2*)&P[(size_t)ids1[r] * IN + 2 * lane];
    float s0 = 0.f, s1 = 0.f;
    #pragma unroll
    for (int kk = 0; kk < 10; ++kk) {
        const bf16x2 v = *(const bf16x2*)&P[(size_t)ids2[base + kk] * IN + HIDC + 2 * lane];
        s0 += (float)v.x; s1 += (float)v.y;
    }
    const bf16x2 ox = {(__bf16)fmaxf((float)vx.x + bxv.x, 0.f),
                       (__bf16)fmaxf((float)vx.y + bxv.y, 0.f)};
    const bf16x2 on = {(__bf16)fmaxf(s0 * 0.1f + bnv.x, 0.f),
                       (__bf16)fmaxf(s1 * 0.1f + bnv.y, 0.f)};
    *(bf16x2*)&h1[(size_t)r * IN + 2 * lane]        = ox;
    *(bf16x2*)&h1[(size_t)r * IN + HIDC + 2 * lane] = on;
}

// ---------------- Kernel C: per output row, 256 threads ---------------------
__global__ __launch_bounds__(256) void k_out2(
    const int* __restrict__ ids, const int* __restrict__ ids1,
    const __bf16* __restrict__ P, const __bf16* __restrict__ h1,
    const float* __restrict__ bx1, const float* __restrict__ bn1,
    const float* __restrict__ Wx2, const float* __restrict__ bx2,
    const float* __restrict__ Wn2, const float* __restrict__ bn2,
    const float* __restrict__ Wfc, const float* __restrict__ bfc,
    float* __restrict__ out)
{
    __shared__ float h0[IN];
    __shared__ float mh[IN];
    __shared__ float red[4];
    __shared__ float fcred[7][4];
    const int i = blockIdx.x;
    const int c = threadIdx.x;

    // mean25(h1) — contiguous rows
    {
        float sh = 0.f;
        for (int kk = 0; kk < 25; ++kk)
            sh += (float)h1[(size_t)(i * 25 + kk) * IN + c];
        mh[c] = sh * 0.04f;
    }
    // h0 = relu([Px[ids[i]] + bx1 ; mean25(Pn[ids1 rows]) + bn1])
    if (c < HIDC) {
        h0[c] = fmaxf((float)P[(size_t)ids[i] * IN + c] + bx1[c], 0.f);
    } else {
        float s = 0.f;
        for (int kk = 0; kk < 25; ++kk)
            s += (float)P[(size_t)ids1[i * 25 + kk] * IN + c];  // Pn col c-128 lives at row offset c
        h0[c] = fmaxf(s * 0.04f + bn1[c - HIDC], 0.f);
    }
    __syncthreads();

    // layer 2 GEMV: g0[c]
    const int  jj = c & 127;
    const bool nb = (c >= HIDC);
    const float* __restrict__ W = nb ? Wn2 : Wx2;
    const float* __restrict__ X = nb ? mh : h0;
    float g = (nb ? bn2 : bx2)[jj];
    #pragma unroll 4
    for (int k = 0; k < IN; ++k)
        g = fmaf(X[k], W[(size_t)k * HIDC + jj], g);

    // L2 norm over 256 dims
    float sq = g * g;
    #pragma unroll
    for (int off = 32; off > 0; off >>= 1) sq += __shfl_down(sq, off);
    if ((c & 63) == 0) red[c >> 6] = sq;
    __syncthreads();
    const float total = red[0] + red[1] + red[2] + red[3];
    const float inv = 1.f / fmaxf(sqrtf(total), 1e-12f);
    const float p = g * inv;

    // fc
    #pragma unroll
    for (int q = 0; q < 7; ++q) {
        float t = p * Wfc[(size_t)c * 7 + q];
        #pragma unroll
        for (int off = 32; off > 0; off >>= 1) t += __shfl_down(t, off);
        if ((c & 63) == 0) fcred[q][c >> 6] = t;
    }
    __syncthreads();
    if (c < 7) {
        out[(size_t)i * 7 + c] =
            fcred[c][0] + fcred[c][1] + fcred[c][2] + fcred[c][3] + bfc[c];
    }
}

extern "C" void kernel_launch(void* const* d_in, const int* in_sizes, int n_in,
                              void* d_out, int out_size, void* d_ws, size_t ws_size,
                              hipStream_t stream) {
    const int*   ids   = (const int*)d_in[0];
    const int*   ids1  = (const int*)d_in[1];
    const int*   ids2  = (const int*)d_in[2];
    const float* feats = (const float*)d_in[3];
    const float* Wx1   = (const float*)d_in[4];
    const float* bx1   = (const float*)d_in[5];
    const float* Wn1   = (const float*)d_in[6];
    const float* bn1   = (const float*)d_in[7];
    const float* Wx2   = (const float*)d_in[8];
    const float* bx2   = (const float*)d_in[9];
    const float* Wn2   = (const float*)d_in[10];
    const float* bn2   = (const float*)d_in[11];
    const float* Wfc   = (const float*)d_in[12];
    const float* bfc   = (const float*)d_in[13];
    float* out = (float*)d_out;

    __bf16* P   = (__bf16*)d_ws;                       // [100000][256] bf16 = 51.2 MB
    __bf16* h1  = P  + (size_t)NNODE * IN;             // [12800][256] bf16 = 6.55 MB
    __bf16* WtH = h1 + (size_t)ROWS1 * IN;             // [256][256] bf16
    __bf16* WtL = WtH + (size_t)IN * IN;

    k_wprep<<<256, 256, 0, stream>>>(Wx1, Wn1, WtH, WtL);
    k_P<<<(NNODE + 63) / 64, 256, 0, stream>>>(feats, WtH, WtL, P);
    k_h1s<<<ROWS1 / 8, 512, 0, stream>>>(ids1, ids2, P, bx1, bn1, h1);
    k_out2<<<512, 256, 0, stream>>>(ids, ids1, P, h1, bx1, bn1,
                                    Wx2, bx2, Wn2, bn2, Wfc, bfc, out);
}

// Round 8
// 82.853 us; speedup vs baseline: 1.3797x; 1.3797x over previous
//
#include <hip/hip_runtime.h>
#include <hip/hip_bf16.h>

// GraphSAGE 2-layer forward, fused topology:
//   k_wprep: Wt = [Wx1|Wn1] cols, bf16 hi/lo
//   k_fused: per 16-row tile: gather f1 + mean10(f2) -> bf16 LDS -> MFMA
//            h1 = relu([f1@Wx1 ; mean10(f2)@Wn1] + b)  (bf16 out)
//   k_out:   per output row: h0, g0, normalize, FC
// Precision: A bf16-hi, W 2-pass hi+lo MFMA (round-6 numerics, absmax ~5e-4).

typedef __bf16 bf16x8 __attribute__((ext_vector_type(8)));
typedef __bf16 bf16x4 __attribute__((ext_vector_type(4)));
typedef float  f32x4  __attribute__((ext_vector_type(4)));

constexpr int IN    = 256;
constexpr int HIDC  = 128;
constexpr int ROWS1 = 512 * 25;   // 12800

// ---------------- Kernel P0: Wt = [Wx1|Wn1] columns as bf16 hi/lo -----------
// WtH/WtL[j][k], j in [0,256): j<128 -> Wx1 col j, else Wn1 col j-128.
__global__ __launch_bounds__(256) void k_wprep(
    const float* __restrict__ Wx, const float* __restrict__ Wn,
    __bf16* __restrict__ WtH, __bf16* __restrict__ WtL)
{
    const int j = blockIdx.x;
    const int k = threadIdx.x;
    const float v = (j < HIDC) ? Wx[(size_t)k * HIDC + j]
                               : Wn[(size_t)k * HIDC + (j - HIDC)];
    const __bf16 h = (__bf16)v;
    const __bf16 l = (__bf16)(v - (float)h);
    const size_t o = (size_t)j * IN + k;
    WtH[o] = h;
    WtL[o] = l;
}

// ---------------- Kernel F: fused gather + MFMA for h1 ----------------------
// Block = 16 rows, 512 thr = 8 waves. Wave w stages rows 2w,2w+1 (11 x 1KB
// gathers each), converts to bf16 in XOR-swizzled LDS. Then wave w computes
// branch (w&1), col-group (w>>1)*32: 16 rows x 32 cols, 2-pass MFMA.
// Cross-block wave overlap hides MFMA+B-loads under other blocks' gathers.
__global__ __launch_bounds__(512) void k_fused(
    const int* __restrict__ ids1, const int* __restrict__ ids2,
    const float* __restrict__ feats,
    const __bf16* __restrict__ WtH, const __bf16* __restrict__ WtL,
    const float* __restrict__ bx, const float* __restrict__ bn,
    __bf16* __restrict__ h1)
{
    __shared__ __bf16 a0[16 * IN];   // f1 rows (bf16-hi)
    __shared__ __bf16 a1[16 * IN];   // mean10(f2) rows (bf16-hi)
    const int tid  = threadIdx.x;
    const int w    = tid >> 6;
    const int lane = tid & 63;
    const int r0   = blockIdx.x * 16;

    // ---- stage: wave w handles rows 2w, 2w+1 (f32 gathers, bf16 to LDS)
    #pragma unroll
    for (int i = 0; i < 2; ++i) {
        const int rr = 2 * w + i;
        const int r  = r0 + rr;
        const float4 v1 = ((const float4*)(feats + (size_t)ids1[r] * IN))[lane];
        float4 acc = make_float4(0.f, 0.f, 0.f, 0.f);
        const int base = r * 10;
        #pragma unroll
        for (int kk = 0; kk < 10; ++kk) {
            const float4 v = ((const float4*)(feats + (size_t)ids2[base + kk] * IN))[lane];
            acc.x += v.x; acc.y += v.y; acc.z += v.z; acc.w += v.w;
        }
        acc.x *= 0.1f; acc.y *= 0.1f; acc.z *= 0.1f; acc.w *= 0.1f;

        const int e  = (rr << 8) + lane * 4;
        const int es = e ^ ((rr & 7) << 3);        // 16B-slot XOR swizzle
        const bf16x4 h0v = {(__bf16)v1.x, (__bf16)v1.y, (__bf16)v1.z, (__bf16)v1.w};
        const bf16x4 h1v = {(__bf16)acc.x, (__bf16)acc.y, (__bf16)acc.z, (__bf16)acc.w};
        *(bf16x4*)&a0[es] = h0v;
        *(bf16x4*)&a1[es] = h1v;
    }
    __syncthreads();

    // ---- compute: wave w -> branch br = w&1, col-group cg = w>>1 (32 cols)
    const int br  = w & 1;
    const int cg  = w >> 1;
    const int l15 = lane & 15;
    const int lk  = lane >> 4;
    const __bf16* __restrict__ As = br ? a1 : a0;
    const __bf16* __restrict__ WH = WtH + (size_t)br * HIDC * IN;
    const __bf16* __restrict__ WL = WtL + (size_t)br * HIDC * IN;

    const f32x4 z = {0.f, 0.f, 0.f, 0.f};
    f32x4 acc[2] = {z, z};

    for (int k0 = 0; k0 < IN; k0 += 32) {
        int ea = (l15 << 8) + k0 + lk * 8;
        ea ^= (l15 & 7) << 3;
        const bf16x8 a = *(const bf16x8*)&As[ea];
        #pragma unroll
        for (int ct = 0; ct < 2; ++ct) {
            const size_t eb = (size_t)(cg * 32 + ct * 16 + l15) * IN + k0 + lk * 8;
            const bf16x8 bH = *(const bf16x8*)&WH[eb];
            const bf16x8 bL = *(const bf16x8*)&WL[eb];
            acc[ct] = __builtin_amdgcn_mfma_f32_16x16x32_bf16(a, bH, acc[ct], 0, 0, 0);
            acc[ct] = __builtin_amdgcn_mfma_f32_16x16x32_bf16(a, bL, acc[ct], 0, 0, 0);
        }
    }

    // ---- epilogue: C/D col=lane&15, row=(lane>>4)*4+reg; relu + bias, bf16
    const float* __restrict__ bias = br ? bn : bx;
    #pragma unroll
    for (int ct = 0; ct < 2; ++ct) {
        const int colL = cg * 32 + ct * 16 + l15;      // 0..127 within branch
        const float bv = bias[colL];
        #pragma unroll
        for (int q = 0; q < 4; ++q) {
            const int rr = lk * 4 + q;
            h1[(size_t)(r0 + rr) * IN + br * HIDC + colL] =
                (__bf16)fmaxf(acc[ct][q] + bv, 0.f);
        }
    }
}

// ---------------- Kernel C: per output row, 512 threads ---------------------
__global__ __launch_bounds__(512) void k_out(
    const int* __restrict__ ids, const int* __restrict__ ids1,
    const float* __restrict__ feats, const __bf16* __restrict__ h1,
    const float* __restrict__ Wx1, const float* __restrict__ bx1,
    const float* __restrict__ Wn1, const float* __restrict__ bn1,
    const float* __restrict__ Wx2, const float* __restrict__ bx2,
    const float* __restrict__ Wn2, const float* __restrict__ bn2,
    const float* __restrict__ Wfc, const float* __restrict__ bfc,
    float* __restrict__ out)
{
    __shared__ float x0[IN];
    __shared__ float m1[IN];
    __shared__ float mh[IN];
    __shared__ float h0[IN];
    __shared__ float g0[IN];
    __shared__ float partA[2][IN];
    __shared__ float partB[2][IN];
    __shared__ float red[8];
    __shared__ float fcred[7][4];
    const int i   = blockIdx.x;
    const int tid = threadIdx.x;
    const int c   = tid & 255;
    const int h   = tid >> 8;

    float s = 0.f, sh = 0.f;
    for (int kk = h; kk < 25; kk += 2) {
        const int r = i * 25 + kk;
        s  += feats[(size_t)ids1[r] * IN + c];
        sh += (float)h1[(size_t)r * IN + c];
    }
    if (h == 0) x0[c] = feats[(size_t)ids[i] * IN + c];
    partA[h][c] = s;
    partB[h][c] = sh;
    __syncthreads();
    if (h == 0) m1[c] = (partA[0][c] + partA[1][c]) * 0.04f;
    else        mh[c] = (partB[0][c] + partB[1][c]) * 0.04f;
    __syncthreads();

    const int  jj = c & 127;
    const bool nb = (c >= 128);
    {
        const float* __restrict__ W = nb ? Wn1 : Wx1;
        const float* __restrict__ X = nb ? m1 : x0;
        float acc = 0.f;
        #pragma unroll 4
        for (int k = h * 128; k < h * 128 + 128; ++k)
            acc = fmaf(X[k], W[(size_t)k * HIDC + jj], acc);
        partA[h][c] = acc;
    }
    __syncthreads();
    if (h == 0)
        h0[c] = fmaxf(partA[0][c] + partA[1][c] + (nb ? bn1 : bx1)[jj], 0.f);
    __syncthreads();
    {
        const float* __restrict__ W = nb ? Wn2 : Wx2;
        const float* __restrict__ X = nb ? mh : h0;
        float acc = 0.f;
        #pragma unroll 4
        for (int k = h * 128; k < h * 128 + 128; ++k)
            acc = fmaf(X[k], W[(size_t)k * HIDC + jj], acc);
        partB[h][c] = acc;
    }
    __syncthreads();
    if (h == 0)
        g0[c] = partB[0][c] + partB[1][c] + (nb ? bn2 : bx2)[jj];
    __syncthreads();

    {
        const float gv = g0[c];
        float sq = gv * gv;
        #pragma unroll
        for (int off = 32; off > 0; off >>= 1) sq += __shfl_down(sq, off);
        if ((tid & 63) == 0) red[tid >> 6] = sq;
    }
    __syncthreads();
    const float total = (red[0] + red[1] + red[2] + red[3] +
                         red[4] + red[5] + red[6] + red[7]) * 0.5f;
    const float inv = 1.f / fmaxf(sqrtf(total), 1e-12f);
    const float p = g0[c] * inv;

    const int qbase = h * 4;
    const int qn    = h ? 3 : 4;
    for (int q = qbase; q < qbase + qn; ++q) {
        float t = p * Wfc[(size_t)c * 7 + q];
        #pragma unroll
        for (int off = 32; off > 0; off >>= 1) t += __shfl_down(t, off);
        if ((tid & 63) == 0) fcred[q][(tid >> 6) & 3] = t;
    }
    __syncthreads();
    if (tid < 7) {
        out[(size_t)i * 7 + tid] =
            fcred[tid][0] + fcred[tid][1] + fcred[tid][2] + fcred[tid][3] + bfc[tid];
    }
}

extern "C" void kernel_launch(void* const* d_in, const int* in_sizes, int n_in,
                              void* d_out, int out_size, void* d_ws, size_t ws_size,
                              hipStream_t stream) {
    const int*   ids   = (const int*)d_in[0];
    const int*   ids1  = (const int*)d_in[1];
    const int*   ids2  = (const int*)d_in[2];
    const float* feats = (const float*)d_in[3];
    const float* Wx1   = (const float*)d_in[4];
    const float* bx1   = (const float*)d_in[5];
    const float* Wn1   = (const float*)d_in[6];
    const float* bn1   = (const float*)d_in[7];
    const float* Wx2   = (const float*)d_in[8];
    const float* bx2   = (const float*)d_in[9];
    const float* Wn2   = (const float*)d_in[10];
    const float* bn2   = (const float*)d_in[11];
    const float* Wfc   = (const float*)d_in[12];
    const float* bfc   = (const float*)d_in[13];
    float* out = (float*)d_out;

    __bf16* h1  = (__bf16*)d_ws;                      // [12800][256] bf16 = 6.55 MB
    __bf16* WtH = h1 + (size_t)ROWS1 * IN;            // [256][256] bf16
    __bf16* WtL = WtH + (size_t)IN * IN;

    k_wprep<<<256, 256, 0, stream>>>(Wx1, Wn1, WtH, WtL);
    k_fused<<<ROWS1 / 16, 512, 0, stream>>>(ids1, ids2, feats, WtH, WtL,
                                            bx1, bn1, h1);
    k_out<<<512, 512, 0, stream>>>(ids, ids1, feats, h1,
                                   Wx1, bx1, Wn1, bn1,
                                   Wx2, bx2, Wn2, bn2,
                                   Wfc, bfc, out);
}